// Round 3
// baseline (10732.433 us; speedup 1.0000x reference)
//
#include <hip/hip_runtime.h>
#include <math.h>

#define HH 96
#define WW 96
#define HW 9216
#define TT 5

typedef __attribute__((ext_vector_type(8))) short bf16x8;
typedef __attribute__((ext_vector_type(4))) float f32x4;

__device__ __forceinline__ float sigf(float x) { return 1.0f / (1.0f + expf(-x)); }

// split fp32 -> hi/lo bf16 (truncation; hi+lo carries ~24 bits)
__device__ __forceinline__ unsigned short bhi(float x) {
    return (unsigned short)(__float_as_uint(x) >> 16);
}
__device__ __forceinline__ unsigned short blo(float x) {
    float h = __uint_as_float((__float_as_uint(x) >> 16) << 16);
    return (unsigned short)(__float_as_uint(x - h) >> 16);
}

// ---------------------------------------------------------------------------
// MFMA implicit-GEMM 3x3 conv, pad=1, fp32-accurate via K-tripled hi/lo split.
// Block: 256 thr (4 waves). Tile: 16 rows x 16 cols x 64 oc.
// Wave w: rows w*4..w*4+3, all 64 oc -> 16 C-frags (16px x 16oc each).
// K' = 3*IC expanded channels, chunked by 32 (one MFMA K).
// LDS: sA [18 rows][18 cols][exp 32 pad->40]; sB [9 taps][64 oc][exp pad 40].
// ---------------------------------------------------------------------------
template<int ICA, int ICB, bool PERM_OUT>
__global__ __launch_bounds__(256) void conv3x3_mfma(
    const float* __restrict__ srcA, long strideA,
    const float* __restrict__ srcB, long strideB,
    const float* __restrict__ wgt,  const float* __restrict__ bias,
    float* __restrict__ out, long strideOut, int OC)
{
    constexpr int IC = ICA + ICB;
    constexpr int NCH = (3 * IC) / 32;   // k-chunks
    __shared__ unsigned short sA[18 * 18 * 40];
    __shared__ unsigned short sB[9 * 64 * 40];

    const int tid  = threadIdx.x;
    const int wave = tid >> 6;
    const int lane = tid & 63;
    const int m    = lane & 15;
    const int quad = lane >> 4;

    const int tY = blockIdx.x / 6;
    const int tX = blockIdx.x % 6;
    const int ocBase = blockIdx.y * 64;
    const int img = blockIdx.z;

    long outImg;
    if (PERM_OUT) {
        int t = img >> 1, b = img & 1;
        outImg = (long)(b * TT + t) * strideOut;
    } else {
        outImg = (long)img * strideOut;
    }

    const float* baseA = srcA + (long)img * strideA;

    f32x4 acc[4][4];
#pragma unroll
    for (int rr = 0; rr < 4; ++rr)
#pragma unroll
        for (int of = 0; of < 4; ++of) acc[rr][of] = (f32x4){0.f, 0.f, 0.f, 0.f};

    for (int chunk = 0; chunk < NCH; ++chunk) {
        const int kbase = chunk * 32;
        __syncthreads();
        // ---- stage A: 32 exp-slots x 18x18 pixels
        for (int i = tid; i < 32 * 324; i += 256) {
            int e_l = i / 324;
            int rc = i - e_l * 324;
            int row = rc / 18;
            int col = rc - row * 18;
            int e = kbase + e_l;
            int c = e / 3;
            int rol = e - c * 3;          // A roles: {hi, hi, lo}
            int gy = tY * 16 + row - 1;
            int gx = tX * 16 + col - 1;
            float v = 0.f;
            if (gy >= 0 && gy < HH && gx >= 0 && gx < WW) {
                if (ICB == 0) {
                    v = baseA[(long)c * HW + gy * WW + gx];
                } else {
                    if (c < ICA) v = baseA[(long)c * HW + gy * WW + gx];
                    else v = srcB[(long)img * strideB + (long)(c - ICA) * HW + gy * WW + gx];
                }
            }
            sA[rc * 40 + e_l] = (rol == 2) ? blo(v) : bhi(v);
        }
        // ---- stage B: 9 taps x 64 oc x 32 exp-slots
        for (int i = tid; i < 9 * 64 * 32; i += 256) {
            int e_l = i & 31;
            int r = i >> 5;
            int ocl = r & 63;
            int tap = r >> 6;
            int e = kbase + e_l;
            int c = e / 3;
            int rol = e - c * 3;          // B roles: {hi, lo, hi}
            int oc = ocBase + ocl;
            float v = 0.f;
            if (oc < OC) v = wgt[((long)oc * IC + c) * 9 + tap];
            sB[(tap * 64 + ocl) * 40 + e_l] = (rol == 1) ? blo(v) : bhi(v);
        }
        __syncthreads();

        // ---- compute
#pragma unroll
        for (int kx = 0; kx < 3; ++kx) {
            bf16x8 a[6];
#pragma unroll
            for (int q = 0; q < 6; ++q) {
                const unsigned short* ap =
                    &sA[((wave * 4 + q) * 18 + (m + kx)) * 40 + quad * 8];
                a[q] = *(const bf16x8*)ap;
            }
#pragma unroll
            for (int ky = 0; ky < 3; ++ky) {
                const int tap = ky * 3 + kx;
#pragma unroll
                for (int of = 0; of < 4; ++of) {
                    const unsigned short* bp =
                        &sB[(tap * 64 + of * 16 + m) * 40 + quad * 8];
                    bf16x8 b = *(const bf16x8*)bp;
#pragma unroll
                    for (int rr = 0; rr < 4; ++rr) {
                        acc[rr][of] = __builtin_amdgcn_mfma_f32_16x16x32_bf16(
                            a[rr + ky], b, acc[rr][of], 0, 0, 0);
                    }
                }
            }
        }
    }

    // ---- epilogue: C-frag row=(quad*4+reg)=pixel col, col=lane&15=oc
    const int gy0 = tY * 16 + wave * 4;
    const int gx0 = tX * 16 + quad * 4;
#pragma unroll
    for (int of = 0; of < 4; ++of) {
        const int oc = ocBase + of * 16 + m;
        if (oc < OC) {
            const float bv = bias[oc];
#pragma unroll
            for (int rr = 0; rr < 4; ++rr) {
                float* op = out + outImg + (long)oc * HW + (gy0 + rr) * WW + gx0;
                op[0] = acc[rr][of].x + bv;
                op[1] = acc[rr][of].y + bv;
                op[2] = acc[rr][of].z + bv;
                op[3] = acc[rr][of].w + bv;
            }
        }
    }
}

// ---------------------------------------------------------------------------
// Deformable sampling: one thread per (b, g, k, pixel).
// ---------------------------------------------------------------------------
__global__ __launch_bounds__(256) void dcn_sample_kernel(
    const float* __restrict__ h,    // [B][64][HW]
    const float* __restrict__ om,   // [B][216][HW]
    float* __restrict__ samp)       // [B][576][HW]
{
    int i = blockIdx.x * 256 + threadIdx.x;
    int p = i % HW;
    int r = i / HW;
    int k = r % 9;
    int g = (r / 9) % 8;
    int b = r / 72;
    int y = p / WW, x = p - (p / WW) * WW;
    int ky = k / 3, kx = k - ky * 3;

    const float* omb = om + (long)b * 216 * HW;
    float offy = omb[(g * 18 + k * 2) * HW + p];
    float offx = omb[(g * 18 + k * 2 + 1) * HW + p];
    float mm = sigf(omb[(144 + g * 9 + k) * HW + p]);

    float py = (float)(y + ky - 1) + offy;
    float px = (float)(x + kx - 1) + offx;
    float y0f = floorf(py), x0f = floorf(px);
    float wy = py - y0f, wx = px - x0f;
    int y0 = (int)y0f, x0 = (int)x0f;
    int y1 = y0 + 1, x1 = x0 + 1;

    bool vy0 = (y0 >= 0) && (y0 < HH), vy1 = (y1 >= 0) && (y1 < HH);
    bool vx0 = (x0 >= 0) && (x0 < WW), vx1 = (x1 >= 0) && (x1 < WW);
    int cy0 = min(max(y0, 0), HH - 1), cy1 = min(max(y1, 0), HH - 1);
    int cx0 = min(max(x0, 0), WW - 1), cx1 = min(max(x1, 0), WW - 1);
    int i00 = cy0 * WW + cx0, i01 = cy0 * WW + cx1;
    int i10 = cy1 * WW + cx0, i11 = cy1 * WW + cx1;
    float w00 = (1.f - wy) * (1.f - wx) * ((vy0 && vx0) ? mm : 0.f);
    float w01 = (1.f - wy) * wx         * ((vy0 && vx1) ? mm : 0.f);
    float w10 = wy * (1.f - wx)         * ((vy1 && vx0) ? mm : 0.f);
    float w11 = wy * wx                 * ((vy1 && vx1) ? mm : 0.f);

    const float* hb = h + ((long)b * 64 + g * 8) * HW;
    float* sb = samp + ((long)b * 576 + (long)(g * 8) * 9 + k) * HW + p;
#pragma unroll
    for (int cg = 0; cg < 8; ++cg) {
        const float* hp = hb + (long)cg * HW;
        float v = w00 * hp[i00] + w01 * hp[i01] + w10 * hp[i10] + w11 * hp[i11];
        sb[(long)(cg * 9) * HW] = v;
    }
}

// ---------------------------------------------------------------------------
// 1x1 "conv" (the DCN einsum), fp32 VALU (converted next round).
// ---------------------------------------------------------------------------
__global__ __launch_bounds__(256) void conv1x1_relu_kernel(
    const float* __restrict__ src,   // [B][576][HW]
    const float* __restrict__ wgt,   // [128][576]
    const float* __restrict__ bias,  // [128]
    float* __restrict__ out)         // [B][128][HW]
{
    __shared__ float sX[8][256];
    __shared__ float sWk[8][32];
    const int tid = threadIdx.x;
    const int pt = blockIdx.x;
    const int ocBase = blockIdx.y * 32;
    const int b = blockIdx.z;

    const int ocq = tid & 7;
    const int pg = tid >> 3;
    const int oc_l = ocq * 4;
    const int px = pg * 8;

    float acc[4][8];
#pragma unroll
    for (int o = 0; o < 4; ++o)
#pragma unroll
        for (int j = 0; j < 8; ++j) acc[o][j] = 0.f;

    const float* sbase = src + (long)b * 576 * HW + pt * 256;

    for (int c0 = 0; c0 < 576; c0 += 8) {
        for (int i = tid; i < 2048; i += 256) {
            int icl = i >> 8; int p = i & 255;
            sX[icl][p] = sbase[(long)(c0 + icl) * HW + p];
        }
        {
            int icl = tid >> 5; int ocl = tid & 31;
            sWk[icl][ocl] = wgt[(long)(ocBase + ocl) * 576 + c0 + icl];
        }
        __syncthreads();
#pragma unroll
        for (int icl = 0; icl < 8; ++icl) {
            float wa[4], xv[8];
#pragma unroll
            for (int o = 0; o < 4; ++o) wa[o] = sWk[icl][oc_l + o];
#pragma unroll
            for (int j = 0; j < 8; ++j) xv[j] = sX[icl][px + j];
#pragma unroll
            for (int o = 0; o < 4; ++o)
#pragma unroll
                for (int j = 0; j < 8; ++j)
                    acc[o][j] = fmaf(wa[o], xv[j], acc[o][j]);
        }
        __syncthreads();
    }

#pragma unroll
    for (int o = 0; o < 4; ++o) {
        int oc = ocBase + oc_l + o;
        float bv = bias[oc];
        float* op = out + (long)b * 128 * HW + (long)oc * HW + pt * 256 + px;
#pragma unroll
        for (int j = 0; j < 8; ++j) op[j] = fmaxf(acc[o][j] + bv, 0.f);
    }
}

// ---------------------------------------------------------------------------
// LSTM gates
// ---------------------------------------------------------------------------
__global__ __launch_bounds__(256) void gates_kernel(
    const float* __restrict__ cc,
    float* __restrict__ h, float* __restrict__ c,
    float* __restrict__ hseq)
{
    int i = blockIdx.x * 256 + threadIdx.x;
    int p = i % (64 * HW);
    int b = i / (64 * HW);
    const float* ccb = cc + (long)b * 256 * HW;
    float ci = ccb[p];
    float cf = ccb[64 * HW + p];
    float co = ccb[128 * HW + p];
    float cg = ccb[192 * HW + p];
    float cold = c[i];
    float c2 = sigf(cf) * cold + sigf(ci) * tanhf(cg);
    float h2 = sigf(co) * tanhf(c2);
    c[i] = c2;
    h[i] = h2;
    hseq[i] = h2;
}

// ---------------------------------------------------------------------------
extern "C" void kernel_launch(void* const* d_in, const int* in_sizes, int n_in,
                              void* d_out, int out_size, void* d_ws, size_t ws_size,
                              hipStream_t stream)
{
    const float* input  = (const float*)d_in[0];
    const float* fuse_w = (const float*)d_in[1];
    const float* fuse_b = (const float*)d_in[2];
    const float* om_w   = (const float*)d_in[3];
    const float* om_b   = (const float*)d_in[4];
    const float* dcn_w  = (const float*)d_in[5];
    const float* dcn_b  = (const float*)d_in[6];
    const float* conv_w = (const float*)d_in[7];
    const float* conv_b = (const float*)d_in[8];
    const float* cat_w  = (const float*)d_in[9];
    const float* cat_b  = (const float*)d_in[10];
    float* out = (float*)d_out;

    const long CHW = 64L * HW;
    float* ws = (float*)d_ws;
    float* hseq  = ws;                        // [2][T][B][64][HW]
    float* hbuf  = hseq + 20L * CHW;
    float* cbuf  = hbuf + 2L * CHW;
    float* comb  = cbuf + 2L * CHW;
    float* om    = comb + 2L * CHW;           // [B][216][HW]
    float* samp  = om + 2L * 216 * HW;        // [B][576][HW]
    float* fused = samp + 2L * 576 * HW;      // [B][128][HW]
    float* cc    = samp;                      // alias

    dim3 blk(256);
    for (int dir = 0; dir < 2; ++dir) {
        hipMemsetAsync(hbuf, 0, (size_t)(4L * CHW) * sizeof(float), stream);
        for (int s = 0; s < TT; ++s) {
            int t = (dir == 0) ? s : (TT - 1 - s);
            conv3x3_mfma<64, 64, false><<<dim3(36, 1, 2), blk, 0, stream>>>(
                input + (long)t * CHW, (long)TT * CHW, hbuf, CHW,
                fuse_w, fuse_b, comb, CHW, 64);
            conv3x3_mfma<64, 0, false><<<dim3(36, 4, 2), blk, 0, stream>>>(
                comb, CHW, nullptr, 0, om_w, om_b, om, 216L * HW, 216);
            dcn_sample_kernel<<<dim3(5184), blk, 0, stream>>>(hbuf, om, samp);
            conv1x1_relu_kernel<<<dim3(36, 4, 2), blk, 0, stream>>>(samp, dcn_w, dcn_b, fused);
            conv3x3_mfma<128, 0, false><<<dim3(36, 4, 2), blk, 0, stream>>>(
                fused, 128L * HW, nullptr, 0, conv_w, conv_b, cc, 256L * HW, 256);
            gates_kernel<<<dim3(4608), blk, 0, stream>>>(
                cc, hbuf, cbuf, hseq + ((long)dir * TT + t) * 2L * CHW);
        }
    }
    conv3x3_mfma<64, 64, true><<<dim3(36, 1, 10), blk, 0, stream>>>(
        hseq, CHW, hseq + 10L * CHW, CHW, cat_w, cat_b, out, CHW, 64);
}

// Round 4
// 3661.650 us; speedup vs baseline: 2.9310x; 2.9310x over previous
//
#include <hip/hip_runtime.h>
#include <math.h>

#define HH 96
#define WW 96
#define HW 9216
#define TT 5

typedef __attribute__((ext_vector_type(8))) short bf16x8;
typedef __attribute__((ext_vector_type(4))) float f32x4;

__device__ __forceinline__ float sigf(float x) { return 1.0f / (1.0f + expf(-x)); }
__device__ __forceinline__ unsigned short bhi(float x) {
    return (unsigned short)(__float_as_uint(x) >> 16);
}
__device__ __forceinline__ unsigned short blo(float x) {
    float h = __uint_as_float(__float_as_uint(x) & 0xffff0000u);
    return (unsigned short)(__float_as_uint(x - h) >> 16);
}

// ---------------------------------------------------------------------------
// Weight expansion: src [OC][IC][9] fp32 -> dst [9][OCP][2][IC] bf16 hi/lo.
// ---------------------------------------------------------------------------
__global__ __launch_bounds__(256) void wexp3_kernel(
    const float* __restrict__ w, unsigned short* __restrict__ dst,
    int OC, int OCP, int IC)
{
    long i = (long)blockIdx.x * 256 + threadIdx.x;   // over 9*OCP*IC
    int ic = (int)(i % IC);
    long r = i / IC;
    int oc = (int)(r % OCP);
    int tap = (int)(r / OCP);
    float v = (oc < OC) ? w[((long)oc * IC + ic) * 9 + tap] : 0.f;
    long base = (((long)tap * OCP + oc) * 2) * IC + ic;
    dst[base] = bhi(v);
    dst[base + IC] = blo(v);
}

// dcn_w [128][576] -> [128][2][576]
__global__ __launch_bounds__(256) void wexp1_kernel(
    const float* __restrict__ w, unsigned short* __restrict__ dst)
{
    int i = blockIdx.x * 256 + threadIdx.x;   // 128*576
    int k = i % 576;
    int oc = i / 576;
    float v = w[i];
    dst[((long)oc * 2) * 576 + k] = bhi(v);
    dst[((long)oc * 2 + 1) * 576 + k] = blo(v);
}

// input [b][t][64][HW] fp32 -> xbf [(t*2+b)][p][64] bf16 (single plane)
__global__ __launch_bounds__(256) void xprep_kernel(
    const float* __restrict__ input, unsigned short* __restrict__ xbf)
{
    long i = (long)blockIdx.x * 256 + threadIdx.x;  // 10*64*HW
    int p = (int)(i % HW);
    long r = i / HW;
    int c = (int)(r % 64);
    long bt = r / 64;                 // b*5 + t
    int b = (int)(bt / TT), t = (int)(bt % TT);
    float v = input[i];
    xbf[(((long)(t * 2 + b) * HW) + p) * 64 + c] = bhi(v);
}

// ---------------------------------------------------------------------------
// MFMA implicit-GEMM 3x3 conv. M = oc, N = pixels.
// Block: 256 thr (4 waves). Pixel tile 8 rows x 16 cols; oc-tile 64.
// Wave w handles rows w*2..w*2+1 (2 N-frags) x 4 M-frags.
// Input: NHWC bf16, optionally hi/lo ([p][2C]: hi c, lo C+c), two sources
// split at channel IC1. Weights pre-expanded [9][OCP][2][IC].
// OUTMODE: 0 = fp32 NCHW, 1 = fp32 NCHW with (t,b) permute, 2 = bf16 NHWC.
// ---------------------------------------------------------------------------
template<int IC, int IC1, bool S1LO, bool S2LO, int OUTMODE>
__global__ __launch_bounds__(256) void conv3x3_hl(
    const unsigned short* __restrict__ src1, long s1stride,
    const unsigned short* __restrict__ src2, long s2stride,
    const unsigned short* __restrict__ wexp,
    const float* __restrict__ bias,
    float* __restrict__ outF, unsigned short* __restrict__ outH,
    long outStride, int OC)
{
    constexpr int NCH = IC / 32;
    constexpr bool ANYLO = S1LO || S2LO;
    constexpr int CS = ANYLO ? 68 : 36;
    __shared__ unsigned short sX[180 * CS];

    const int tid  = threadIdx.x;
    const int wave = tid >> 6;
    const int lane = tid & 63;
    const int m    = lane & 15;
    const int quad = lane >> 4;

    const int tY = blockIdx.x / 6;       // 12 row tiles (8 rows each)
    const int tX = blockIdx.x % 6;       // 6 col tiles (16 cols each)
    const int ocb = blockIdx.y * 64;
    const int OCP = gridDim.y * 64;
    const int img = blockIdx.z;

    f32x4 acc[4][2];
#pragma unroll
    for (int mf = 0; mf < 4; ++mf)
#pragma unroll
        for (int nf = 0; nf < 2; ++nf) acc[mf][nf] = (f32x4){0.f, 0.f, 0.f, 0.f};

#pragma unroll
    for (int chunk = 0; chunk < NCH; ++chunk) {
        constexpr int dummy = 0; (void)dummy;
        const bool isS1 = (chunk * 32 < IC1);
        const bool cHL = isS1 ? S1LO : S2LO;
        const unsigned short* sp;
        int C1, chloc;
        if (isS1) { sp = src1 + (long)img * s1stride; C1 = IC1; chloc = chunk * 32; }
        else      { sp = src2 + (long)img * s2stride; C1 = IC - IC1; chloc = chunk * 32 - IC1; }
        const int pstr = cHL ? 2 * C1 : C1;

        __syncthreads();
        // ---- stage pixels: 10 rows x 18 cols halo tile, 32 ch (x2 planes)
        for (int pl = 0; pl <= (cHL ? 1 : 0); ++pl) {
            for (int i = tid; i < 720; i += 256) {
                int cell = i >> 2, g = i & 3;
                int row = cell / 18, col = cell - row * 18;
                int gy = tY * 8 + row - 1;
                int gx = tX * 16 + col - 1;
                bf16x8 v = (bf16x8){0,0,0,0,0,0,0,0};
                if (gy >= 0 && gy < HH && gx >= 0 && gx < WW) {
                    long off = (long)(gy * WW + gx) * pstr + pl * C1 + chloc + g * 8;
                    v = *(const bf16x8*)(sp + off);
                }
                *(bf16x8*)&sX[cell * CS + pl * 32 + g * 8] = v;
            }
        }
        __syncthreads();

#pragma unroll
        for (int kx = 0; kx < 3; ++kx) {
            bf16x8 Bh[4], Bl[4];
#pragma unroll
            for (int rr = 0; rr < 4; ++rr) {
                int cell = (wave * 2 + rr) * 18 + kx + m;
                Bh[rr] = *(const bf16x8*)&sX[cell * CS + quad * 8];
                if (ANYLO && cHL)
                    Bl[rr] = *(const bf16x8*)&sX[cell * CS + 32 + quad * 8];
            }
#pragma unroll
            for (int ky = 0; ky < 3; ++ky) {
                const int tap = ky * 3 + kx;
                bf16x8 Ah[4], Al[4];
#pragma unroll
                for (int mf = 0; mf < 4; ++mf) {
                    const unsigned short* wp = wexp +
                        (((long)tap * OCP + ocb + mf * 16 + m) * 2) * IC + chunk * 32 + quad * 8;
                    Ah[mf] = *(const bf16x8*)wp;
                    Al[mf] = *(const bf16x8*)(wp + IC);
                }
#pragma unroll
                for (int mf = 0; mf < 4; ++mf) {
#pragma unroll
                    for (int nf = 0; nf < 2; ++nf) {
                        const int rr = nf + ky;
                        acc[mf][nf] = __builtin_amdgcn_mfma_f32_16x16x32_bf16(
                            Ah[mf], Bh[rr], acc[mf][nf], 0, 0, 0);
                        acc[mf][nf] = __builtin_amdgcn_mfma_f32_16x16x32_bf16(
                            Al[mf], Bh[rr], acc[mf][nf], 0, 0, 0);
                        if (ANYLO && cHL)
                            acc[mf][nf] = __builtin_amdgcn_mfma_f32_16x16x32_bf16(
                                Ah[mf], Bl[rr], acc[mf][nf], 0, 0, 0);
                    }
                }
            }
        }
    }

    // ---- epilogue. D: row(quad*4+reg)=oc-within-frag, col(lane&15)=pixel.
    if (OUTMODE == 2) {
#pragma unroll
        for (int mf = 0; mf < 4; ++mf) {
            int ocl = ocb + mf * 16 + quad * 4;
            float b0 = bias[ocl], b1 = bias[ocl + 1], b2 = bias[ocl + 2], b3 = bias[ocl + 3];
#pragma unroll
            for (int nf = 0; nf < 2; ++nf) {
                int p = (tY * 8 + wave * 2 + nf) * WW + tX * 16 + m;
                ushort4 hv;
                hv.x = bhi(acc[mf][nf].x + b0);
                hv.y = bhi(acc[mf][nf].y + b1);
                hv.z = bhi(acc[mf][nf].z + b2);
                hv.w = bhi(acc[mf][nf].w + b3);
                *(ushort4*)&outH[(long)img * HW * 64 + (long)p * OC + ocl] = hv;
            }
        }
    } else {
        long imgOut;
        if (OUTMODE == 1) {
            int t = img >> 1, b = img & 1;
            imgOut = (long)(b * TT + t) * outStride;
        } else {
            imgOut = (long)img * outStride;
        }
        const int gxb = tX * 16 + m;
#pragma unroll
        for (int mf = 0; mf < 4; ++mf) {
#pragma unroll
            for (int reg = 0; reg < 4; ++reg) {
                int oc = ocb + mf * 16 + quad * 4 + reg;
                if (oc < OC) {
                    float bv = bias[oc];
#pragma unroll
                    for (int nf = 0; nf < 2; ++nf) {
                        int gy = tY * 8 + wave * 2 + nf;
                        outF[imgOut + (long)oc * HW + gy * WW + gxb] = acc[mf][nf][reg] + bv;
                    }
                }
            }
        }
    }
}

// ---------------------------------------------------------------------------
// Deformable sampling: h fp32 NCHW + om fp32 NCHW -> samp bf16 NHWC [b][p][576]
// ---------------------------------------------------------------------------
__global__ __launch_bounds__(256) void dcn_sample_kernel(
    const float* __restrict__ h,
    const float* __restrict__ om,
    unsigned short* __restrict__ samp)
{
    int i = blockIdx.x * 256 + threadIdx.x;   // B*G*KK*HW
    int p = i % HW;
    int r = i / HW;
    int k = r % 9;
    int g = (r / 9) % 8;
    int b = r / 72;
    int y = p / WW, x = p - (p / WW) * WW;
    int ky = k / 3, kx = k - ky * 3;

    const float* omb = om + (long)b * 216 * HW;
    float offy = omb[(g * 18 + k * 2) * HW + p];
    float offx = omb[(g * 18 + k * 2 + 1) * HW + p];
    float mm = sigf(omb[(144 + g * 9 + k) * HW + p]);

    float py = (float)(y + ky - 1) + offy;
    float px = (float)(x + kx - 1) + offx;
    float y0f = floorf(py), x0f = floorf(px);
    float wy = py - y0f, wx = px - x0f;
    int y0 = (int)y0f, x0 = (int)x0f;
    int y1 = y0 + 1, x1 = x0 + 1;

    bool vy0 = (y0 >= 0) && (y0 < HH), vy1 = (y1 >= 0) && (y1 < HH);
    bool vx0 = (x0 >= 0) && (x0 < WW), vx1 = (x1 >= 0) && (x1 < WW);
    int cy0 = min(max(y0, 0), HH - 1), cy1 = min(max(y1, 0), HH - 1);
    int cx0 = min(max(x0, 0), WW - 1), cx1 = min(max(x1, 0), WW - 1);
    int i00 = cy0 * WW + cx0, i01 = cy0 * WW + cx1;
    int i10 = cy1 * WW + cx0, i11 = cy1 * WW + cx1;
    float w00 = (1.f - wy) * (1.f - wx) * ((vy0 && vx0) ? mm : 0.f);
    float w01 = (1.f - wy) * wx         * ((vy0 && vx1) ? mm : 0.f);
    float w10 = wy * (1.f - wx)         * ((vy1 && vx0) ? mm : 0.f);
    float w11 = wy * wx                 * ((vy1 && vx1) ? mm : 0.f);

    const float* hb = h + ((long)b * 64 + g * 8) * HW;
    unsigned short* sb = samp + ((long)b * HW + p) * 576 + (g * 8) * 9 + k;
#pragma unroll
    for (int cg = 0; cg < 8; ++cg) {
        const float* hp = hb + (long)cg * HW;
        float v = w00 * hp[i00] + w01 * hp[i01] + w10 * hp[i10] + w11 * hp[i11];
        sb[cg * 9] = bhi(v);
    }
}

// ---------------------------------------------------------------------------
// 1x1 DCN einsum, MFMA 2-product. samp [b][p][576] bf16 -> fused [b][p][256] hl.
// Block: 64 px x 128 oc. Wave w: M-frags {w*2, w*2+1}, 4 N-frags shared.
// ---------------------------------------------------------------------------
__global__ __launch_bounds__(256) void conv1x1_hl(
    const unsigned short* __restrict__ samp,
    const unsigned short* __restrict__ w1,   // [128][2][576]
    const float* __restrict__ bias,
    unsigned short* __restrict__ fused)      // [b][p][256]
{
    __shared__ unsigned short sX[64 * 72];
    const int tid  = threadIdx.x;
    const int wave = tid >> 6;
    const int lane = tid & 63;
    const int m    = lane & 15;
    const int quad = lane >> 4;
    const int pt = blockIdx.x;     // 144 pixel tiles of 64
    const int b  = blockIdx.y;

    const unsigned short* sbase = samp + (long)b * HW * 576 + (long)pt * 64 * 576;

    f32x4 acc[2][4];
#pragma unroll
    for (int mm = 0; mm < 2; ++mm)
#pragma unroll
        for (int nf = 0; nf < 4; ++nf) acc[mm][nf] = (f32x4){0.f, 0.f, 0.f, 0.f};

    for (int c2 = 0; c2 < 18; c2 += 2) {
        __syncthreads();
        for (int i = tid; i < 512; i += 256) {
            int cell = i >> 3, g = i & 7;
            bf16x8 v = *(const bf16x8*)(sbase + (long)cell * 576 + c2 * 32 + g * 8);
            *(bf16x8*)&sX[cell * 72 + g * 8] = v;
        }
        __syncthreads();
#pragma unroll
        for (int sub = 0; sub < 2; ++sub) {
            const int ch = c2 + sub;
            bf16x8 Bf[4];
#pragma unroll
            for (int nf = 0; nf < 4; ++nf)
                Bf[nf] = *(const bf16x8*)&sX[(nf * 16 + m) * 72 + sub * 32 + quad * 8];
#pragma unroll
            for (int mm = 0; mm < 2; ++mm) {
                const int mf = wave * 2 + mm;
                const unsigned short* wp = w1 + ((long)(mf * 16 + m) * 2) * 576 + ch * 32 + quad * 8;
                bf16x8 Ah = *(const bf16x8*)wp;
                bf16x8 Al = *(const bf16x8*)(wp + 576);
#pragma unroll
                for (int nf = 0; nf < 4; ++nf) {
                    acc[mm][nf] = __builtin_amdgcn_mfma_f32_16x16x32_bf16(Ah, Bf[nf], acc[mm][nf], 0, 0, 0);
                    acc[mm][nf] = __builtin_amdgcn_mfma_f32_16x16x32_bf16(Al, Bf[nf], acc[mm][nf], 0, 0, 0);
                }
            }
        }
    }

#pragma unroll
    for (int mm = 0; mm < 2; ++mm) {
        const int mf = wave * 2 + mm;
        int ocl = mf * 16 + quad * 4;
        float b0 = bias[ocl], b1 = bias[ocl + 1], b2 = bias[ocl + 2], b3 = bias[ocl + 3];
#pragma unroll
        for (int nf = 0; nf < 4; ++nf) {
            int p = pt * 64 + nf * 16 + m;
            float v0 = fmaxf(acc[mm][nf].x + b0, 0.f);
            float v1 = fmaxf(acc[mm][nf].y + b1, 0.f);
            float v2 = fmaxf(acc[mm][nf].z + b2, 0.f);
            float v3 = fmaxf(acc[mm][nf].w + b3, 0.f);
            unsigned short* op = fused + ((long)b * HW + p) * 256 + ocl;
            ushort4 hv, lv;
            hv.x = bhi(v0); hv.y = bhi(v1); hv.z = bhi(v2); hv.w = bhi(v3);
            lv.x = blo(v0); lv.y = blo(v1); lv.z = blo(v2); lv.w = blo(v3);
            *(ushort4*)op = hv;
            *(ushort4*)(op + 128) = lv;
        }
    }
}

// ---------------------------------------------------------------------------
// LSTM gates: cc fp32 NCHW -> h,c fp32 NCHW; hbuf hl NHWC; hseq bf16 NHWC slot.
// ---------------------------------------------------------------------------
__global__ __launch_bounds__(256) void gates_kernel(
    const float* __restrict__ cc,
    float* __restrict__ h, float* __restrict__ c,
    unsigned short* __restrict__ hbuf,   // [b][p][128] (hi 0..63, lo 64..127)
    unsigned short* __restrict__ hseq,   // [(t*2+b)][p][128], + dir*64
    int dir)
{
    long i = (long)blockIdx.x * 256 + threadIdx.x;   // 2*64*HW
    int p = (int)(i % HW);
    long r = i / HW;
    int ch = (int)(r % 64);
    int b = (int)(r / 64);
    const float* ccb = cc + (long)b * 256 * HW;
    long q = (long)ch * HW + p;
    float ci = ccb[q];
    float cf = ccb[64 * HW + q];
    float co = ccb[128 * HW + q];
    float cg = ccb[192 * HW + q];
    float cold = c[i];
    float c2 = sigf(cf) * cold + sigf(ci) * tanhf(cg);
    float h2 = sigf(co) * tanhf(c2);
    c[i] = c2;
    h[i] = h2;
    unsigned short* hb = hbuf + ((long)b * HW + p) * 128;
    hb[ch] = bhi(h2);
    hb[64 + ch] = blo(h2);
    hseq[((long)b * HW + p) * 128 + dir * 64 + ch] = bhi(h2);
}

// ---------------------------------------------------------------------------
extern "C" void kernel_launch(void* const* d_in, const int* in_sizes, int n_in,
                              void* d_out, int out_size, void* d_ws, size_t ws_size,
                              hipStream_t stream)
{
    const float* input  = (const float*)d_in[0];
    const float* fuse_w = (const float*)d_in[1];
    const float* fuse_b = (const float*)d_in[2];
    const float* om_w   = (const float*)d_in[3];
    const float* om_b   = (const float*)d_in[4];
    const float* dcn_w  = (const float*)d_in[5];
    const float* dcn_b  = (const float*)d_in[6];
    const float* conv_w = (const float*)d_in[7];
    const float* conv_b = (const float*)d_in[8];
    const float* cat_w  = (const float*)d_in[9];
    const float* cat_b  = (const float*)d_in[10];
    float* out = (float*)d_out;

    char* w = (char*)d_ws;
    size_t off = 0;
    auto alloc = [&](size_t bytes) { void* p = w + off; off += (bytes + 255) & ~(size_t)255; return p; };

    unsigned short* xbf    = (unsigned short*)alloc(10L * HW * 64 * 2);    // [(t*2+b)][p][64]
    unsigned short* hbuf   = (unsigned short*)alloc(2L * HW * 128 * 2);    // [b][p][128] hl
    unsigned short* comb   = (unsigned short*)alloc(2L * HW * 64 * 2);     // [b][p][64]
    float*          omb    = (float*)alloc(2L * 216 * HW * 4);             // [b][216][HW]
    unsigned short* sampb  = (unsigned short*)alloc(2L * HW * 576 * 2);    // [b][p][576]
    unsigned short* fusedb = (unsigned short*)alloc(2L * HW * 256 * 2);    // [b][p][256] hl
    float*          ccb    = (float*)alloc(2L * 256 * HW * 4);             // [b][256][HW]
    float*          hb     = (float*)alloc(2L * 64 * HW * 4);
    float*          cb     = (float*)alloc(2L * 64 * HW * 4);
    unsigned short* hseqb  = (unsigned short*)alloc(10L * HW * 128 * 2);   // [(t*2+b)][p][128]
    unsigned short* Wf = (unsigned short*)alloc(9L * 64 * 2 * 128 * 2);
    unsigned short* Wo = (unsigned short*)alloc(9L * 256 * 2 * 64 * 2);
    unsigned short* Wc = (unsigned short*)alloc(9L * 256 * 2 * 128 * 2);
    unsigned short* Wk = (unsigned short*)alloc(9L * 64 * 2 * 128 * 2);
    unsigned short* W1 = (unsigned short*)alloc(128L * 2 * 576 * 2);

    dim3 blk(256);
    // ---- prep (every launch: ws is re-poisoned)
    wexp3_kernel<<<dim3(288), blk, 0, stream>>>(fuse_w, Wf, 64, 64, 128);
    wexp3_kernel<<<dim3(576), blk, 0, stream>>>(om_w, Wo, 216, 256, 64);
    wexp3_kernel<<<dim3(1152), blk, 0, stream>>>(conv_w, Wc, 256, 256, 128);
    wexp3_kernel<<<dim3(288), blk, 0, stream>>>(cat_w, Wk, 64, 64, 128);
    wexp1_kernel<<<dim3(288), blk, 0, stream>>>(dcn_w, W1);
    xprep_kernel<<<dim3(23040), blk, 0, stream>>>(input, xbf);

    for (int dir = 0; dir < 2; ++dir) {
        hipMemsetAsync(hbuf, 0, 2L * HW * 128 * 2, stream);
        hipMemsetAsync(hb, 0, 2L * 64 * HW * 4, stream);
        hipMemsetAsync(cb, 0, 2L * 64 * HW * 4, stream);
        for (int s = 0; s < TT; ++s) {
            int t = (dir == 0) ? s : (TT - 1 - s);
            // fuse conv: x(single)+h(hl) -> comb (bf16 NHWC, C=64)
            conv3x3_hl<128, 64, false, true, 2><<<dim3(72, 1, 2), blk, 0, stream>>>(
                xbf + (long)t * 2 * HW * 64, (long)HW * 64, hbuf, (long)HW * 128,
                Wf, fuse_b, nullptr, comb, 0, 64);
            // om conv: comb -> om fp32 NCHW (216 ch)
            conv3x3_hl<64, 64, false, false, 0><<<dim3(72, 4, 2), blk, 0, stream>>>(
                comb, (long)HW * 64, comb, 0,
                Wo, om_b, omb, nullptr, 216L * HW, 216);
            // sampling: h,om -> samp bf16 NHWC
            dcn_sample_kernel<<<dim3(5184), blk, 0, stream>>>(hb, omb, sampb);
            // 1x1 einsum + relu -> fused hl NHWC
            conv1x1_hl<<<dim3(144, 2), blk, 0, stream>>>(sampb, W1, dcn_b, fusedb);
            // big conv: fused(hl) -> cc fp32 NCHW (256 ch)
            conv3x3_hl<128, 128, true, true, 0><<<dim3(72, 4, 2), blk, 0, stream>>>(
                fusedb, (long)HW * 256, fusedb, 0,
                Wc, conv_b, ccb, nullptr, 256L * HW, 256);
            // gates
            gates_kernel<<<dim3(4608), blk, 0, stream>>>(
                ccb, hb, cb, hbuf, hseqb + (long)t * 2 * HW * 128, dir);
        }
    }
    // cat conv: hseq (single, C=128) -> out fp32 NCHW with (t,b)->(b,t) permute
    conv3x3_hl<128, 128, false, false, 1><<<dim3(72, 1, 10), blk, 0, stream>>>(
        hseqb, (long)HW * 128, hseqb, 0,
        Wk, cat_b, out, nullptr, 64L * HW, 64);
}

// Round 5
// 2735.616 us; speedup vs baseline: 3.9232x; 1.3385x over previous
//
#include <hip/hip_runtime.h>
#include <math.h>

#define HH 96
#define WW 96
#define HW 9216
#define TT 5

typedef __attribute__((ext_vector_type(8))) short bf16x8;
typedef __attribute__((ext_vector_type(4))) float f32x4;

__device__ __forceinline__ float sigf(float x) { return 1.0f / (1.0f + expf(-x)); }
__device__ __forceinline__ unsigned short bhi(float x) {
    return (unsigned short)(__float_as_uint(x) >> 16);
}
__device__ __forceinline__ unsigned short blo(float x) {
    float h = __uint_as_float(__float_as_uint(x) & 0xffff0000u);
    return (unsigned short)(__float_as_uint(x - h) >> 16);
}

// ---------------------------------------------------------------------------
// Weight expansion: src [OC][IC][9] fp32 -> dst [9][OCP][2][IC] bf16 hi/lo.
// ---------------------------------------------------------------------------
__global__ __launch_bounds__(256) void wexp3_kernel(
    const float* __restrict__ w, unsigned short* __restrict__ dst,
    int OC, int OCP, int IC)
{
    long i = (long)blockIdx.x * 256 + threadIdx.x;   // over 9*OCP*IC
    int ic = (int)(i % IC);
    long r = i / IC;
    int oc = (int)(r % OCP);
    int tap = (int)(r / OCP);
    float v = (oc < OC) ? w[((long)oc * IC + ic) * 9 + tap] : 0.f;
    long base = (((long)tap * OCP + oc) * 2) * IC + ic;
    dst[base] = bhi(v);
    dst[base + IC] = blo(v);
}

// dcn_w [128][576] -> [128][2][576]
__global__ __launch_bounds__(256) void wexp1_kernel(
    const float* __restrict__ w, unsigned short* __restrict__ dst)
{
    int i = blockIdx.x * 256 + threadIdx.x;   // 128*576
    int k = i % 576;
    int oc = i / 576;
    float v = w[i];
    dst[((long)oc * 2) * 576 + k] = bhi(v);
    dst[((long)oc * 2 + 1) * 576 + k] = blo(v);
}

// input [b][t][64][HW] fp32 -> xbf [(t*2+b)][p][64] bf16 (single plane)
__global__ __launch_bounds__(256) void xprep_kernel(
    const float* __restrict__ input, unsigned short* __restrict__ xbf)
{
    long i = (long)blockIdx.x * 256 + threadIdx.x;  // 10*64*HW
    int p = (int)(i % HW);
    long r = i / HW;
    int c = (int)(r % 64);
    long bt = r / 64;                 // b*5 + t
    int b = (int)(bt / TT), t = (int)(bt % TT);
    float v = input[i];
    xbf[(((long)(t * 2 + b) * HW) + p) * 64 + c] = bhi(v);
}

// ---------------------------------------------------------------------------
// MFMA implicit-GEMM 3x3 conv. M = oc (64 per block), N = pixels.
// Block 256 thr / 4 waves. Pixel tile NROWS x 16. Wave grid 2x2:
//   wm = wave&1 -> mf in {wm*2, wm*2+1}; wr = wave>>1 -> rows wr*NH..+NH-1.
// Per kx: batch 12 global A-loads + B window (NH+2 rows, reused across ky),
// then all MFMAs from registers.
// OUTMODE: 0 = fp32 NCHW, 1 = fp32 NCHW + (t,b) permute, 2 = bf16 NHWC.
// ---------------------------------------------------------------------------
template<int IC, int IC1, bool S1LO, bool S2LO, int OUTMODE, int NROWS>
__global__ __launch_bounds__(256) void conv3x3_v2(
    const unsigned short* __restrict__ src1, long s1stride,
    const unsigned short* __restrict__ src2, long s2stride,
    const unsigned short* __restrict__ wexp,
    const float* __restrict__ bias,
    float* __restrict__ outF, unsigned short* __restrict__ outH,
    long outStride, int OC)
{
    constexpr int NCH = IC / 32;
    constexpr int NH = NROWS / 2;          // nf per wave
    constexpr bool ANYLO = S1LO || S2LO;
    constexpr int CST = ANYLO ? 70 : 38;   // ushort stride per cell (odd dwords)
    constexpr int CELLS = (NROWS + 2) * 18;
    __shared__ unsigned short sX[CELLS * CST];

    const int tid  = threadIdx.x;
    const int wave = tid >> 6;
    const int lane = tid & 63;
    const int m    = lane & 15;
    const int quad = lane >> 4;
    const int wm   = wave & 1;
    const int wr   = wave >> 1;

    const int tY = blockIdx.x / 6;
    const int tX = blockIdx.x % 6;
    const int ocb = blockIdx.y * 64;
    const int OCP = gridDim.y * 64;
    const int img = blockIdx.z;

    f32x4 acc[2][NH];
#pragma unroll
    for (int mi = 0; mi < 2; ++mi)
#pragma unroll
        for (int r = 0; r < NH; ++r) acc[mi][r] = (f32x4){0.f, 0.f, 0.f, 0.f};

#pragma unroll
    for (int chunk = 0; chunk < NCH; ++chunk) {
        const bool isS1 = (chunk * 32 < IC1);
        const bool cHL = isS1 ? S1LO : S2LO;
        const unsigned short* sp;
        int C1, chloc;
        if (isS1) { sp = src1 + (long)img * s1stride; C1 = IC1; chloc = chunk * 32; }
        else      { sp = src2 + (long)img * s2stride; C1 = IC - IC1; chloc = chunk * 32 - IC1; }
        const int pstr = cHL ? 2 * C1 : C1;

        __syncthreads();
        // ---- stage pixel halo tile: (NROWS+2) x 18 cells, 32 ch (x2 planes)
        for (int pl = 0; pl <= (cHL ? 1 : 0); ++pl) {
            for (int i = tid; i < CELLS * 4; i += 256) {
                int cell = i >> 2, g = i & 3;
                int row = cell / 18, col = cell - row * 18;
                int gy = tY * NROWS + row - 1;
                int gx = tX * 16 + col - 1;
                bf16x8 v = (bf16x8){0,0,0,0,0,0,0,0};
                if (gy >= 0 && gy < HH && gx >= 0 && gx < WW) {
                    long off = (long)(gy * WW + gx) * pstr + pl * C1 + chloc + g * 8;
                    v = *(const bf16x8*)(sp + off);
                }
                *(bf16x8*)&sX[cell * CST + pl * 32 + g * 8] = v;
            }
        }
        __syncthreads();

#pragma unroll
        for (int kx = 0; kx < 3; ++kx) {
            // ---- B window: NH+2 rows covering all ky, batched LDS reads
            bf16x8 Bh[NH + 2], Bl[NH + 2];
#pragma unroll
            for (int r = 0; r < NH + 2; ++r) {
                int cell = (wr * NH + r) * 18 + kx + m;
                Bh[r] = *(const bf16x8*)&sX[cell * CST + quad * 8];
                if (ANYLO && cHL)
                    Bl[r] = *(const bf16x8*)&sX[cell * CST + 32 + quad * 8];
            }
            // ---- A: all 3 ky x 2 mi x 2 planes batched global loads
            bf16x8 Ah[3][2], Al[3][2];
#pragma unroll
            for (int ky = 0; ky < 3; ++ky) {
                const int tap = ky * 3 + kx;
#pragma unroll
                for (int mi = 0; mi < 2; ++mi) {
                    const unsigned short* wp = wexp +
                        (((long)tap * OCP + ocb + (wm * 2 + mi) * 16 + m) * 2) * IC
                        + chunk * 32 + quad * 8;
                    Ah[ky][mi] = *(const bf16x8*)wp;
                    Al[ky][mi] = *(const bf16x8*)(wp + IC);
                }
            }
            // ---- MFMAs, all operands in registers
#pragma unroll
            for (int ky = 0; ky < 3; ++ky) {
#pragma unroll
                for (int mi = 0; mi < 2; ++mi) {
#pragma unroll
                    for (int r = 0; r < NH; ++r) {
                        acc[mi][r] = __builtin_amdgcn_mfma_f32_16x16x32_bf16(
                            Ah[ky][mi], Bh[r + ky], acc[mi][r], 0, 0, 0);
                        acc[mi][r] = __builtin_amdgcn_mfma_f32_16x16x32_bf16(
                            Al[ky][mi], Bh[r + ky], acc[mi][r], 0, 0, 0);
                        if (ANYLO && cHL)
                            acc[mi][r] = __builtin_amdgcn_mfma_f32_16x16x32_bf16(
                                Ah[ky][mi], Bl[r + ky], acc[mi][r], 0, 0, 0);
                    }
                }
            }
        }
    }

    // ---- epilogue. D: row(quad*4+reg)=oc, col(lane&15)=pixel.
    if (OUTMODE == 2) {
#pragma unroll
        for (int mi = 0; mi < 2; ++mi) {
            int ocl = ocb + (wm * 2 + mi) * 16 + quad * 4;
            float b0 = bias[ocl], b1 = bias[ocl + 1], b2 = bias[ocl + 2], b3 = bias[ocl + 3];
#pragma unroll
            for (int r = 0; r < NH; ++r) {
                int p = (tY * NROWS + wr * NH + r) * WW + tX * 16 + m;
                ushort4 hv;
                hv.x = bhi(acc[mi][r].x + b0);
                hv.y = bhi(acc[mi][r].y + b1);
                hv.z = bhi(acc[mi][r].z + b2);
                hv.w = bhi(acc[mi][r].w + b3);
                *(ushort4*)&outH[(long)img * HW * 64 + (long)p * OC + ocl] = hv;
            }
        }
    } else {
        long imgOut;
        if (OUTMODE == 1) {
            int t = img >> 1, b = img & 1;
            imgOut = (long)(b * TT + t) * outStride;
        } else {
            imgOut = (long)img * outStride;
        }
        const int gxb = tX * 16 + m;
#pragma unroll
        for (int mi = 0; mi < 2; ++mi) {
#pragma unroll
            for (int reg = 0; reg < 4; ++reg) {
                int oc = ocb + (wm * 2 + mi) * 16 + quad * 4 + reg;
                if (oc < OC) {
                    float bv = bias[oc];
#pragma unroll
                    for (int r = 0; r < NH; ++r) {
                        int gy = tY * NROWS + wr * NH + r;
                        outF[imgOut + (long)oc * HW + gy * WW + gxb] = acc[mi][r][reg] + bv;
                    }
                }
            }
        }
    }
}

// ---------------------------------------------------------------------------
// Deformable sampling: h fp32 NCHW + om fp32 NCHW -> samp bf16 NHWC [b][p][576]
// ---------------------------------------------------------------------------
__global__ __launch_bounds__(256) void dcn_sample_kernel(
    const float* __restrict__ h,
    const float* __restrict__ om,
    unsigned short* __restrict__ samp)
{
    int i = blockIdx.x * 256 + threadIdx.x;   // B*G*KK*HW
    int p = i % HW;
    int r = i / HW;
    int k = r % 9;
    int g = (r / 9) % 8;
    int b = r / 72;
    int y = p / WW, x = p - (p / WW) * WW;
    int ky = k / 3, kx = k - ky * 3;

    const float* omb = om + (long)b * 216 * HW;
    float offy = omb[(g * 18 + k * 2) * HW + p];
    float offx = omb[(g * 18 + k * 2 + 1) * HW + p];
    float mm = sigf(omb[(144 + g * 9 + k) * HW + p]);

    float py = (float)(y + ky - 1) + offy;
    float px = (float)(x + kx - 1) + offx;
    float y0f = floorf(py), x0f = floorf(px);
    float wy = py - y0f, wx = px - x0f;
    int y0 = (int)y0f, x0 = (int)x0f;
    int y1 = y0 + 1, x1 = x0 + 1;

    bool vy0 = (y0 >= 0) && (y0 < HH), vy1 = (y1 >= 0) && (y1 < HH);
    bool vx0 = (x0 >= 0) && (x0 < WW), vx1 = (x1 >= 0) && (x1 < WW);
    int cy0 = min(max(y0, 0), HH - 1), cy1 = min(max(y1, 0), HH - 1);
    int cx0 = min(max(x0, 0), WW - 1), cx1 = min(max(x1, 0), WW - 1);
    int i00 = cy0 * WW + cx0, i01 = cy0 * WW + cx1;
    int i10 = cy1 * WW + cx0, i11 = cy1 * WW + cx1;
    float w00 = (1.f - wy) * (1.f - wx) * ((vy0 && vx0) ? mm : 0.f);
    float w01 = (1.f - wy) * wx         * ((vy0 && vx1) ? mm : 0.f);
    float w10 = wy * (1.f - wx)         * ((vy1 && vx0) ? mm : 0.f);
    float w11 = wy * wx                 * ((vy1 && vx1) ? mm : 0.f);

    const float* hb = h + ((long)b * 64 + g * 8) * HW;
    unsigned short* sb = samp + ((long)b * HW + p) * 576 + (g * 8) * 9 + k;
#pragma unroll
    for (int cg = 0; cg < 8; ++cg) {
        const float* hp = hb + (long)cg * HW;
        float v = w00 * hp[i00] + w01 * hp[i01] + w10 * hp[i10] + w11 * hp[i11];
        sb[cg * 9] = bhi(v);
    }
}

// ---------------------------------------------------------------------------
// 1x1 DCN einsum, MFMA 2-product. samp [b][p][576] bf16 -> fused [b][p][256] hl.
// Block: 64 px x 128 oc. Wave w: M-frags {w*2, w*2+1}, 4 N-frags.
// Batched loads per 64-ch k-block; LDS stride 38 dwords (conflict-free).
// ---------------------------------------------------------------------------
__global__ __launch_bounds__(256) void conv1x1_hl(
    const unsigned short* __restrict__ samp,
    const unsigned short* __restrict__ w1,   // [128][2][576]
    const float* __restrict__ bias,
    unsigned short* __restrict__ fused)      // [b][p][256]
{
    __shared__ unsigned short sX[64 * 76];
    const int tid  = threadIdx.x;
    const int wave = tid >> 6;
    const int lane = tid & 63;
    const int m    = lane & 15;
    const int quad = lane >> 4;
    const int pt = blockIdx.x;     // 144 pixel tiles of 64
    const int b  = blockIdx.y;

    const unsigned short* sbase = samp + (long)b * HW * 576 + (long)pt * 64 * 576;

    f32x4 acc[2][4];
#pragma unroll
    for (int mm = 0; mm < 2; ++mm)
#pragma unroll
        for (int nf = 0; nf < 4; ++nf) acc[mm][nf] = (f32x4){0.f, 0.f, 0.f, 0.f};

    for (int cb = 0; cb < 9; ++cb) {
        __syncthreads();
        for (int i = tid; i < 512; i += 256) {
            int cell = i >> 3, g = i & 7;
            bf16x8 v = *(const bf16x8*)(sbase + (long)cell * 576 + cb * 64 + g * 8);
            *(bf16x8*)&sX[cell * 76 + g * 8] = v;
        }
        __syncthreads();
        bf16x8 Bv[2][4];
#pragma unroll
        for (int sub = 0; sub < 2; ++sub)
#pragma unroll
            for (int nf = 0; nf < 4; ++nf)
                Bv[sub][nf] = *(const bf16x8*)&sX[(nf * 16 + m) * 76 + sub * 32 + quad * 8];
        bf16x8 Ah[2][2], Al[2][2];
#pragma unroll
        for (int sub = 0; sub < 2; ++sub)
#pragma unroll
            for (int mm = 0; mm < 2; ++mm) {
                const unsigned short* wp = w1 + ((long)((wave * 2 + mm) * 16 + m) * 2) * 576
                                           + cb * 64 + sub * 32 + quad * 8;
                Ah[sub][mm] = *(const bf16x8*)wp;
                Al[sub][mm] = *(const bf16x8*)(wp + 576);
            }
#pragma unroll
        for (int sub = 0; sub < 2; ++sub)
#pragma unroll
            for (int mm = 0; mm < 2; ++mm)
#pragma unroll
                for (int nf = 0; nf < 4; ++nf) {
                    acc[mm][nf] = __builtin_amdgcn_mfma_f32_16x16x32_bf16(
                        Ah[sub][mm], Bv[sub][nf], acc[mm][nf], 0, 0, 0);
                    acc[mm][nf] = __builtin_amdgcn_mfma_f32_16x16x32_bf16(
                        Al[sub][mm], Bv[sub][nf], acc[mm][nf], 0, 0, 0);
                }
    }

#pragma unroll
    for (int mm = 0; mm < 2; ++mm) {
        const int mf = wave * 2 + mm;
        int ocl = mf * 16 + quad * 4;
        float b0 = bias[ocl], b1 = bias[ocl + 1], b2 = bias[ocl + 2], b3 = bias[ocl + 3];
#pragma unroll
        for (int nf = 0; nf < 4; ++nf) {
            int p = pt * 64 + nf * 16 + m;
            float v0 = fmaxf(acc[mm][nf].x + b0, 0.f);
            float v1 = fmaxf(acc[mm][nf].y + b1, 0.f);
            float v2 = fmaxf(acc[mm][nf].z + b2, 0.f);
            float v3 = fmaxf(acc[mm][nf].w + b3, 0.f);
            unsigned short* op = fused + ((long)b * HW + p) * 256 + ocl;
            ushort4 hv, lv;
            hv.x = bhi(v0); hv.y = bhi(v1); hv.z = bhi(v2); hv.w = bhi(v3);
            lv.x = blo(v0); lv.y = blo(v1); lv.z = blo(v2); lv.w = blo(v3);
            *(ushort4*)op = hv;
            *(ushort4*)(op + 128) = lv;
        }
    }
}

// ---------------------------------------------------------------------------
// LSTM gates: cc fp32 NCHW -> h,c fp32 NCHW; hbuf hl NHWC; hseq bf16 NHWC slot.
// ---------------------------------------------------------------------------
__global__ __launch_bounds__(256) void gates_kernel(
    const float* __restrict__ cc,
    float* __restrict__ h, float* __restrict__ c,
    unsigned short* __restrict__ hbuf,   // [b][p][128] (hi 0..63, lo 64..127)
    unsigned short* __restrict__ hseq,   // [(t*2+b)][p][128], + dir*64
    int dir)
{
    long i = (long)blockIdx.x * 256 + threadIdx.x;   // 2*64*HW
    int p = (int)(i % HW);
    long r = i / HW;
    int ch = (int)(r % 64);
    int b = (int)(r / 64);
    const float* ccb = cc + (long)b * 256 * HW;
    long q = (long)ch * HW + p;
    float ci = ccb[q];
    float cf = ccb[64 * HW + q];
    float co = ccb[128 * HW + q];
    float cg = ccb[192 * HW + q];
    float cold = c[i];
    float c2 = sigf(cf) * cold + sigf(ci) * tanhf(cg);
    float h2 = sigf(co) * tanhf(c2);
    c[i] = c2;
    h[i] = h2;
    unsigned short* hb = hbuf + ((long)b * HW + p) * 128;
    hb[ch] = bhi(h2);
    hb[64 + ch] = blo(h2);
    hseq[((long)b * HW + p) * 128 + dir * 64 + ch] = bhi(h2);
}

// ---------------------------------------------------------------------------
extern "C" void kernel_launch(void* const* d_in, const int* in_sizes, int n_in,
                              void* d_out, int out_size, void* d_ws, size_t ws_size,
                              hipStream_t stream)
{
    const float* input  = (const float*)d_in[0];
    const float* fuse_w = (const float*)d_in[1];
    const float* fuse_b = (const float*)d_in[2];
    const float* om_w   = (const float*)d_in[3];
    const float* om_b   = (const float*)d_in[4];
    const float* dcn_w  = (const float*)d_in[5];
    const float* dcn_b  = (const float*)d_in[6];
    const float* conv_w = (const float*)d_in[7];
    const float* conv_b = (const float*)d_in[8];
    const float* cat_w  = (const float*)d_in[9];
    const float* cat_b  = (const float*)d_in[10];
    float* out = (float*)d_out;

    char* w = (char*)d_ws;
    size_t off = 0;
    auto alloc = [&](size_t bytes) { void* p = w + off; off += (bytes + 255) & ~(size_t)255; return p; };

    unsigned short* xbf    = (unsigned short*)alloc(10L * HW * 64 * 2);    // [(t*2+b)][p][64]
    unsigned short* hbuf   = (unsigned short*)alloc(2L * HW * 128 * 2);    // [b][p][128] hl
    unsigned short* comb   = (unsigned short*)alloc(2L * HW * 64 * 2);     // [b][p][64]
    float*          omb    = (float*)alloc(2L * 216 * HW * 4);             // [b][216][HW]
    unsigned short* sampb  = (unsigned short*)alloc(2L * HW * 576 * 2);    // [b][p][576]
    unsigned short* fusedb = (unsigned short*)alloc(2L * HW * 256 * 2);    // [b][p][256] hl
    float*          ccb    = (float*)alloc(2L * 256 * HW * 4);             // [b][256][HW]
    float*          hb     = (float*)alloc(2L * 64 * HW * 4);
    float*          cb     = (float*)alloc(2L * 64 * HW * 4);
    unsigned short* hseqb  = (unsigned short*)alloc(10L * HW * 128 * 2);   // [(t*2+b)][p][128]
    unsigned short* Wf = (unsigned short*)alloc(9L * 64 * 2 * 128 * 2);
    unsigned short* Wo = (unsigned short*)alloc(9L * 256 * 2 * 64 * 2);
    unsigned short* Wc = (unsigned short*)alloc(9L * 256 * 2 * 128 * 2);
    unsigned short* Wk = (unsigned short*)alloc(9L * 64 * 2 * 128 * 2);
    unsigned short* W1 = (unsigned short*)alloc(128L * 2 * 576 * 2);

    dim3 blk(256);
    // ---- prep (every launch: ws is re-poisoned)
    wexp3_kernel<<<dim3(288), blk, 0, stream>>>(fuse_w, Wf, 64, 64, 128);
    wexp3_kernel<<<dim3(576), blk, 0, stream>>>(om_w, Wo, 216, 256, 64);
    wexp3_kernel<<<dim3(1152), blk, 0, stream>>>(conv_w, Wc, 256, 256, 128);
    wexp3_kernel<<<dim3(288), blk, 0, stream>>>(cat_w, Wk, 64, 64, 128);
    wexp1_kernel<<<dim3(288), blk, 0, stream>>>(dcn_w, W1);
    xprep_kernel<<<dim3(23040), blk, 0, stream>>>(input, xbf);

    for (int dir = 0; dir < 2; ++dir) {
        hipMemsetAsync(hbuf, 0, 2L * HW * 128 * 2, stream);
        hipMemsetAsync(hb, 0, 2L * 64 * HW * 4, stream);
        hipMemsetAsync(cb, 0, 2L * 64 * HW * 4, stream);
        for (int s = 0; s < TT; ++s) {
            int t = (dir == 0) ? s : (TT - 1 - s);
            // fuse conv: x(single)+h(hl) -> comb (bf16 NHWC, C=64)
            conv3x3_v2<128, 64, false, true, 2, 4><<<dim3(144, 1, 2), blk, 0, stream>>>(
                xbf + (long)t * 2 * HW * 64, (long)HW * 64, hbuf, (long)HW * 128,
                Wf, fuse_b, nullptr, comb, 0, 64);
            // om conv: comb -> om fp32 NCHW (216 ch)
            conv3x3_v2<64, 64, false, false, 0, 8><<<dim3(72, 4, 2), blk, 0, stream>>>(
                comb, (long)HW * 64, comb, 0,
                Wo, om_b, omb, nullptr, 216L * HW, 216);
            // sampling: h,om -> samp bf16 NHWC
            dcn_sample_kernel<<<dim3(5184), blk, 0, stream>>>(hb, omb, sampb);
            // 1x1 einsum + relu -> fused hl NHWC
            conv1x1_hl<<<dim3(144, 2), blk, 0, stream>>>(sampb, W1, dcn_b, fusedb);
            // big conv: fused(hl) -> cc fp32 NCHW (256 ch)
            conv3x3_v2<128, 128, true, true, 0, 8><<<dim3(72, 4, 2), blk, 0, stream>>>(
                fusedb, (long)HW * 256, fusedb, 0,
                Wc, conv_b, ccb, nullptr, 256L * HW, 256);
            // gates
            gates_kernel<<<dim3(4608), blk, 0, stream>>>(
                ccb, hb, cb, hbuf, hseqb + (long)t * 2 * HW * 128, dir);
        }
    }
    // cat conv: hseq (single, C=128) -> out fp32 NCHW with (t,b)->(b,t) permute
    conv3x3_v2<128, 128, false, false, 1, 4><<<dim3(144, 1, 10), blk, 0, stream>>>(
        hseqb, (long)HW * 128, hseqb, 0,
        Wk, cat_b, out, nullptr, 64L * HW, 64);
}